// Round 15
// baseline (255.843 us; speedup 1.0000x reference)
//
#include <hip/hip_runtime.h>

#define P_CNT 32768
#define D_DIM 256
#define B_SZ  256
#define INVT  20.0f
#define NEG_BIG -3.0e38f
#define SEGW 32              // slots per (sample, colgroup) segment
#define NSEG 16              // col groups (256 colblocks / 16)
#define CAPT (SEGW*NSEG)     // 512 total per sample
#define LCAP 12              // per-block per-sample LDS list cap (expected 0.8)
#define TC 2.5f              // cross candidate threshold (score)
#define TS 0.40f             // sims candidate threshold
#define MREF 4.5f            // intra LSE fixed reference

typedef _Float16 half8  __attribute__((ext_vector_type(8)));
typedef _Float16 half4v __attribute__((ext_vector_type(4)));
typedef float    floatx4 __attribute__((ext_vector_type(4)));

__device__ __forceinline__ unsigned fkey(float v) {
  unsigned bu = __float_as_uint(v);
  return bu ^ ((unsigned)(((int)bu) >> 31) | 0x80000000u);
}
__device__ __forceinline__ float fdec(unsigned k) {
  unsigned bu = (k & 0x80000000u) ? (k ^ 0x80000000u) : ~k;
  return __uint_as_float(bu);
}

__device__ __forceinline__ float blockSum4(float v, int tid, float* red4) {
#pragma unroll
  for (int off = 1; off < 64; off <<= 1) v += __shfl_xor(v, off);
  if ((tid & 63) == 0) red4[tid >> 6] = v;
  __syncthreads();
  float r = red4[0] + red4[1] + red4[2] + red4[3];
  __syncthreads();
  return r;
}

__device__ __forceinline__ int blockSumI4(int v, int tid, int* redI) {
#pragma unroll
  for (int off = 1; off < 64; off <<= 1) v += __shfl_xor(v, off);
  if ((tid & 63) == 0) redI[tid >> 6] = v;
  __syncthreads();
  int r = redI[0] + redI[1] + redI[2] + redI[3];
  __syncthreads();
  return r;
}

// ---------------- kernel 0: gather prx, A' interleaved: row 2b=feat, 2b+1=mem[prx] ----
__global__ void prep_kernel(const float* __restrict__ features,
                            const int* __restrict__ targets,
                            const int* __restrict__ all_prx,
                            const float* __restrict__ mem,
                            float* __restrict__ A2,
                            int* __restrict__ prxArr) {
  const int b = blockIdx.x;
  const int k = threadIdx.x;
  const int t = targets[b];
  const int pr = all_prx[t];
  if (k == 0) prxArr[b] = pr;
  A2[(size_t)(2 * b) * D_DIM + k] = features[b * D_DIM + k];
  A2[(size_t)(2 * b + 1) * D_DIM + k] = mem[(size_t)pr * D_DIM + k];
}

// ---------------- kernel 1: split-fp16 MFMA GEMM with fused stats epilogue ----------
__global__ __launch_bounds__(256) void gemm_fused(
    const float* __restrict__ A, const float* __restrict__ Bm,
    float* __restrict__ Co,
    const int* __restrict__ prxArr, const int* __restrict__ cams,
    unsigned* __restrict__ maxKey, float* __restrict__ intraS,
    int* __restrict__ cxSeg, float* __restrict__ cxVal, int* __restrict__ cxIdx,
    int* __restrict__ smSeg, float* __restrict__ smVal, int* __restrict__ smIdx) {
  __shared__ _Float16 Ah[128][40], Al[128][40], Bh[128][40], Bl[128][40];
  __shared__ int prxSh[64]; __shared__ int camSh[64];
  __shared__ unsigned pmaxSh[64];
  __shared__ float intraSh[64];
  __shared__ int lcC[64], lcS[64], rsvC[64], rsvS[64];
  __shared__ float lVC[64][LCAP]; __shared__ int lIC[64][LCAP];
  __shared__ float lVS[64][LCAP]; __shared__ int lIS[64][LCAP];

  const int tid = threadIdx.x;
  const int lane = tid & 63;
  const int wid = tid >> 6;
  const int wr = wid >> 1, wc = wid & 1;
  const int orig = (blockIdx.x & 7) * 128 + (blockIdx.x >> 3);
  const int rowBase = (orig & 3) << 7;
  const int colBase = (orig >> 2) << 7;
  const int sBase = (orig & 3) << 6;        // 64 samples per row-block
  const int g = (orig >> 2) >> 4;           // col group [0,16)

  if (tid < 64) {
    prxSh[tid] = prxArr[sBase + tid];
    camSh[tid] = cams[sBase + tid];
    pmaxSh[tid] = 0u;
    intraSh[tid] = 0.f;
    lcC[tid] = 0; lcS[tid] = 0;
  }

  const int trow = tid >> 3;
  const int tseg = tid & 7;
  floatx4 acc[4][4];
#pragma unroll
  for (int i = 0; i < 4; ++i)
#pragma unroll
    for (int j = 0; j < 4; ++j) {
      acc[i][j][0] = 0.f; acc[i][j][1] = 0.f; acc[i][j][2] = 0.f; acc[i][j][3] = 0.f;
    }
  const int fr = lane & 15;
  const int kg = (lane >> 4) << 3;

  for (int step = 0; step < 8; ++step) {
    const int k0 = step << 5;
    float4 sa[4], sb[4];
#pragma unroll
    for (int p = 0; p < 4; ++p) {
      const int r = trow + (p << 5);
      sa[p] = *(const float4*)(A  + (size_t)(rowBase + r) * D_DIM + k0 + tseg * 4);
      sb[p] = *(const float4*)(Bm + (size_t)(colBase + r) * D_DIM + k0 + tseg * 4);
    }
    __syncthreads();
#pragma unroll
    for (int p = 0; p < 4; ++p) {
      const int r = trow + (p << 5);
      float4 v = sa[p];
      half4v h, l;
      h[0] = (_Float16)v.x; l[0] = (_Float16)(v.x - (float)h[0]);
      h[1] = (_Float16)v.y; l[1] = (_Float16)(v.y - (float)h[1]);
      h[2] = (_Float16)v.z; l[2] = (_Float16)(v.z - (float)h[2]);
      h[3] = (_Float16)v.w; l[3] = (_Float16)(v.w - (float)h[3]);
      *(half4v*)&Ah[r][tseg * 4] = h;
      *(half4v*)&Al[r][tseg * 4] = l;
      v = sb[p];
      h[0] = (_Float16)v.x; l[0] = (_Float16)(v.x - (float)h[0]);
      h[1] = (_Float16)v.y; l[1] = (_Float16)(v.y - (float)h[1]);
      h[2] = (_Float16)v.z; l[2] = (_Float16)(v.z - (float)h[2]);
      h[3] = (_Float16)v.w; l[3] = (_Float16)(v.w - (float)h[3]);
      *(half4v*)&Bh[r][tseg * 4] = h;
      *(half4v*)&Bl[r][tseg * 4] = l;
    }
    __syncthreads();
    half8 ah[4], al[4], bh[4], bl[4];
#pragma unroll
    for (int f = 0; f < 4; ++f) {
      ah[f] = *(const half8*)&Ah[wr * 64 + f * 16 + fr][kg];
      al[f] = *(const half8*)&Al[wr * 64 + f * 16 + fr][kg];
      bh[f] = *(const half8*)&Bh[wc * 64 + f * 16 + fr][kg];
      bl[f] = *(const half8*)&Bl[wc * 64 + f * 16 + fr][kg];
    }
#pragma unroll
    for (int fm = 0; fm < 4; ++fm)
#pragma unroll
      for (int fn = 0; fn < 4; ++fn) {
        acc[fm][fn] = __builtin_amdgcn_mfma_f32_16x16x32_f16(ah[fm], bh[fn], acc[fm][fn], 0, 0, 0);
        acc[fm][fn] = __builtin_amdgcn_mfma_f32_16x16x32_f16(ah[fm], bl[fn], acc[fm][fn], 0, 0, 0);
        acc[fm][fn] = __builtin_amdgcn_mfma_f32_16x16x32_f16(al[fm], bh[fn], acc[fm][fn], 0, 0, 0);
      }
  }

  // ---- fused epilogue: OUT write + per-sample stats (rows 2s=score, 2s+1=memsim) ----
  const int rsub = (lane >> 4) << 2;
#pragma unroll
  for (int fm = 0; fm < 4; ++fm) {
    const int lr0 = wr * 64 + fm * 16 + rsub;    // even
    const int slA = lr0 >> 1;
    const int slB = slA + 1;
    const int camA = camSh[slA], camB = camSh[slB];
    const int pbA = prxSh[slA] & ~7, pbB = prxSh[slB] & ~7;
    const bool icA = ((fr & 7) == camA), icB = ((fr & 7) == camB);
    float mxA = NEG_BIG, mxB = NEG_BIG, eiA = 0.f, eiB = 0.f;
#pragma unroll
    for (int fn = 0; fn < 4; ++fn) {
      const int col = colBase + wc * 64 + fn * 16 + fr;
      const size_t r0 = (size_t)(rowBase + lr0) * P_CNT + col;
      const float scA = acc[fm][fn][0], msA = acc[fm][fn][1];
      const float scB = acc[fm][fn][2], msB = acc[fm][fn][3];
      Co[r0] = scA; Co[r0 + P_CNT] = msA;
      Co[r0 + 2 * (size_t)P_CNT] = scB; Co[r0 + 3 * (size_t)P_CNT] = msB;
      mxA = fmaxf(mxA, scA); mxB = fmaxf(mxB, scB);
      if (icA) eiA += expf((scA - MREF) * INVT);
      if (icB) eiB += expf((scB - MREF) * INVT);
      if (scA > TC && (unsigned)(col - pbA) >= 8u) {
        int t = atomicAdd(&lcC[slA], 1);
        if (t < LCAP) { lVC[slA][t] = scA; lIC[slA][t] = col; }
      }
      if (scB > TC && (unsigned)(col - pbB) >= 8u) {
        int t = atomicAdd(&lcC[slB], 1);
        if (t < LCAP) { lVC[slB][t] = scB; lIC[slB][t] = col; }
      }
      const float smA = 0.15f * scA + 0.85f * msA;
      const float smB = 0.15f * scB + 0.85f * msB;
      if (smA > TS) {
        int t = atomicAdd(&lcS[slA], 1);
        if (t < LCAP) { lVS[slA][t] = smA; lIS[slA][t] = col; }
      }
      if (smB > TS) {
        int t = atomicAdd(&lcS[slB], 1);
        if (t < LCAP) { lVS[slB][t] = smB; lIS[slB][t] = col; }
      }
    }
    atomicMax(&pmaxSh[slA], fkey(mxA));
    atomicMax(&pmaxSh[slB], fkey(mxB));
    if (icA && eiA > 0.f) atomicAdd(&intraSh[slA], eiA);
    if (icB && eiB > 0.f) atomicAdd(&intraSh[slB], eiB);
  }
  __syncthreads();
  if (tid < 64) {
    const int S = sBase + tid;
    atomicMax(&maxKey[S], pmaxSh[tid]);
    const float e = intraSh[tid];
    if (e > 0.f) atomicAdd(&intraS[S], e);
    const int nC = lcC[tid];
    rsvC[tid] = (nC > 0) ? atomicAdd(&cxSeg[S * NSEG + g], (nC > LCAP) ? 1000000 : nC) : 0;
    const int nS = lcS[tid];
    rsvS[tid] = (nS > 0) ? atomicAdd(&smSeg[S * NSEG + g], (nS > LCAP) ? 1000000 : nS) : 0;
  }
  __syncthreads();
  for (int i = tid; i < 64 * LCAP; i += 256) {
    const int sl = i / LCAP, k = i % LCAP;
    const size_t segBase = ((size_t)(sBase + sl) * NSEG + g) * SEGW;
    if (k < min(lcC[sl], LCAP)) {
      int o = rsvC[sl] + k;
      if (o < SEGW) { cxVal[segBase + o] = lVC[sl][k]; cxIdx[segBase + o] = lIC[sl][k]; }
    }
    if (k < min(lcS[sl], LCAP)) {
      int o = rsvS[sl] + k;
      if (o < SEGW) { smVal[segBase + o] = lVS[sl][k]; smIdx[segBase + o] = lIS[sl][k]; }
    }
  }
}

// ---------------- helper: block count of elements above threshold -------------
__device__ int countAbove(const float* Srow, const float* Mrow, int mode,
                          float T, int posBase, int tid, int* redI) {
  int c = 0;
  for (int i = tid; i < P_CNT; i += 256) {
    float v = (mode == 0) ? Srow[i] : (0.15f * Srow[i] + 0.85f * Mrow[i]);
    bool ok = (mode == 0) ? ((unsigned)(i - posBase) >= 8u) : true;
    if (ok && v > T) c++;
  }
  return blockSumI4(c, tid, redI);
}

// ---------------- kernel FIXUP: exact fallback (early-exits normally) ----------
__global__ __launch_bounds__(256) void fixup(
    const float* __restrict__ OUT, const int* __restrict__ prxArr,
    const unsigned* __restrict__ maxKey,
    int* __restrict__ cxSeg, float* __restrict__ cxVal, int* __restrict__ cxIdx,
    int* __restrict__ smSeg, float* __restrict__ smVal, int* __restrict__ smIdx) {
  __shared__ int redI[4];
  __shared__ int flags[4];
  __shared__ int cnt;
  const int b = blockIdx.x;
  const int tid = threadIdx.x;
  const float* Srow = OUT + (size_t)(2 * b) * P_CNT;
  const float* Mrow = Srow + P_CNT;
  const int posBase = prxArr[b] & ~7;

  if (tid == 0) {
    int t = 0, bad = 0;
    for (int g2 = 0; g2 < NSEG; ++g2) {
      int c = cxSeg[b * NSEG + g2];
      if (c > SEGW) bad = 1;
      t += min(c, SEGW);
    }
    flags[0] = t; flags[1] = bad;
    t = 0; bad = 0;
    for (int g2 = 0; g2 < NSEG; ++g2) {
      int c = smSeg[b * NSEG + g2];
      if (c > SEGW) bad = 1;
      t += min(c, SEGW);
    }
    flags[2] = t; flags[3] = bad;
  }
  __syncthreads();

  if (flags[1] || flags[0] < 50) {           // rebuild cross exactly
    float M = fdec(maxKey[b]);
    float lo = M - 1.0f;
    int c = countAbove(Srow, Mrow, 0, lo, posBase, tid, redI);
    for (int it = 0; it < 24 && c < 50; ++it) {
      lo -= (M - lo);
      c = countAbove(Srow, Mrow, 0, lo, posBase, tid, redI);
    }
    float hi = M;
    for (int it = 0; it < 32 && c > CAPT; ++it) {
      float mid = 0.5f * (lo + hi);
      int cm = countAbove(Srow, Mrow, 0, mid, posBase, tid, redI);
      if (cm >= 50) { lo = mid; c = cm; } else hi = mid;
    }
    if (tid == 0) cnt = 0;
    __syncthreads();
    for (int i = tid; i < P_CNT; i += 256) {
      float v = Srow[i];
      if (v > lo && (unsigned)(i - posBase) >= 8u) {
        int t = atomicAdd(&cnt, 1);
        if (t < CAPT) { cxVal[(size_t)b * CAPT + t] = v; cxIdx[(size_t)b * CAPT + t] = i; }
      }
    }
    __syncthreads();
    if (tid == 0) {
      cxSeg[b * NSEG] = 2000000 + min(cnt, CAPT);
      for (int g2 = 1; g2 < NSEG; ++g2) cxSeg[b * NSEG + g2] = 0;
    }
  }
  __syncthreads();

  if (flags[3] || flags[2] < 53) {           // rebuild sims exactly
    float mx = NEG_BIG;
    for (int i = tid; i < P_CNT; i += 256)
      mx = fmaxf(mx, 0.15f * Srow[i] + 0.85f * Mrow[i]);
#pragma unroll
    for (int off = 1; off < 64; off <<= 1) mx = fmaxf(mx, __shfl_xor(mx, off));
    if ((tid & 63) == 0) redI[tid >> 6] = __float_as_int(mx);
    __syncthreads();
    float M = fmaxf(fmaxf(__int_as_float(redI[0]), __int_as_float(redI[1])),
                    fmaxf(__int_as_float(redI[2]), __int_as_float(redI[3])));
    __syncthreads();
    float lo = M - 0.3f;
    int c = countAbove(Srow, Mrow, 1, lo, posBase, tid, redI);
    for (int it = 0; it < 24 && c < 53; ++it) {
      lo -= (M - lo);
      c = countAbove(Srow, Mrow, 1, lo, posBase, tid, redI);
    }
    float hi = M;
    for (int it = 0; it < 32 && c > CAPT; ++it) {
      float mid = 0.5f * (lo + hi);
      int cm = countAbove(Srow, Mrow, 1, mid, posBase, tid, redI);
      if (cm >= 53) { lo = mid; c = cm; } else hi = mid;
    }
    if (tid == 0) cnt = 0;
    __syncthreads();
    for (int i = tid; i < P_CNT; i += 256) {
      float v = 0.15f * Srow[i] + 0.85f * Mrow[i];
      if (v > lo) {
        int t = atomicAdd(&cnt, 1);
        if (t < CAPT) { smVal[(size_t)b * CAPT + t] = v; smIdx[(size_t)b * CAPT + t] = i; }
      }
    }
    __syncthreads();
    if (tid == 0) {
      smSeg[b * NSEG] = 2000000 + min(cnt, CAPT);
      for (int g2 = 1; g2 < NSEG; ++g2) smSeg[b * NSEG + g2] = 0;
    }
  }
}

// ---------------- kernel MERGE: per-sample exact rank + losses (256 blocks) ----
__global__ __launch_bounds__(256) void merge(
    const float* __restrict__ OUT, const int* __restrict__ prxArr,
    const unsigned* __restrict__ maxKey, const float* __restrict__ intraS,
    const int* __restrict__ cxSeg, const float* __restrict__ cxVal,
    const int* __restrict__ cxIdx,
    const int* __restrict__ smSeg, const float* __restrict__ smVal,
    const int* __restrict__ smIdx,
    float* __restrict__ intraArr, float* __restrict__ crossArr,
    float* __restrict__ onlArr) {
  __shared__ __align__(16) float vb[CAPT + 4];
  __shared__ __align__(16) int   ib[CAPT + 4];
  __shared__ __align__(16) float vs[CAPT + 4];
  __shared__ __align__(16) int   is_[CAPT + 4];
  __shared__ int segCntC[NSEG], segDstC[NSEG], segCntS[NSEG], segDstS[NSEG];
  __shared__ int CtotSh[2];
  __shared__ unsigned long long camPk[8];
  __shared__ float red4[4];
  __shared__ int ch[3];
  __shared__ float sbuf[56];
  __shared__ int scnt;

  const int b = blockIdx.x;
  const int tid = threadIdx.x;
  const float* Srow = OUT + (size_t)(2 * b) * P_CNT;
  const int pr = prxArr[b];
  const int posBase = pr & ~7;

  if (tid == 0) {
    int o = 0;
    int c0 = cxSeg[b * NSEG];
    if (c0 >= 2000000) {
      segDstC[0] = 0; segCntC[0] = min(c0 - 2000000, CAPT);
      for (int g2 = 1; g2 < NSEG; ++g2) { segDstC[g2] = 0; segCntC[g2] = 0; }
      o = segCntC[0];
    } else {
      for (int g2 = 0; g2 < NSEG; ++g2) {
        int c = min(cxSeg[b * NSEG + g2], SEGW);
        segDstC[g2] = o; segCntC[g2] = c; o += c;
      }
    }
    CtotSh[0] = o;
  }
  if (tid == 1) {
    int o = 0;
    int c0 = smSeg[b * NSEG];
    if (c0 >= 2000000) {
      segDstS[0] = 0; segCntS[0] = min(c0 - 2000000, CAPT);
      for (int g2 = 1; g2 < NSEG; ++g2) { segDstS[g2] = 0; segCntS[g2] = 0; }
      o = segCntS[0];
    } else {
      for (int g2 = 0; g2 < NSEG; ++g2) {
        int c = min(smSeg[b * NSEG + g2], SEGW);
        segDstS[g2] = o; segCntS[g2] = c; o += c;
      }
    }
    CtotSh[1] = o;
  }
  if (tid == 2) scnt = 0;
  if (tid >= 8 && tid < 16) camPk[tid - 8] = 0ull;
  if (tid == 3) intraArr[b] = -((Srow[pr] - MREF) * INVT - logf(intraS[b]));
  __syncthreads();

  const int C = CtotSh[0], C2 = CtotSh[1];
  const int Cp = (C + 3) & ~3;
  const int C2p = (C2 + 3) & ~3;

  // stage both lists
  for (int g2 = 0; g2 < NSEG; ++g2) {
    const int n = segCntC[g2], d = segDstC[g2];
    const size_t sb_ = ((size_t)b * NSEG + g2) * SEGW;
    for (int i = tid; i < n; i += 256) { vb[d + i] = cxVal[sb_ + i]; ib[d + i] = cxIdx[sb_ + i]; }
    const int n2 = segCntS[g2], d2 = segDstS[g2];
    for (int i = tid; i < n2; i += 256) { vs[d2 + i] = smVal[sb_ + i]; is_[d2 + i] = smIdx[sb_ + i]; }
  }
  if (tid >= 240 && tid < 244) {
    int i = C + (tid - 240);
    if (i < Cp) { vb[i] = NEG_BIG; ib[i] = 0x7fffffff; }
  }
  if (tid >= 244 && tid < 248) {
    int i = C2 + (tid - 244);
    if (i < C2p) { vs[i] = NEG_BIG; is_[i] = 0x7fffffff; }
  }
  __syncthreads();

  // per-cam argmax from sims list (value, smaller index wins)
  for (int i = tid; i < C2; i += 256) {
    float v = vs[i]; int ix = is_[i];
    unsigned long long pk = ((unsigned long long)fkey(v) << 32) | (unsigned)(~(unsigned)ix);
    atomicMax(&camPk[ix & 7], pk);
  }
  __syncthreads();
  if (tid == 96) {
    unsigned used = 0;
    for (int k = 0; k < 3; ++k) {
      unsigned long long best = 0; int bc = 0;
      for (int c = 0; c < 8; ++c)
        if (!((used >> c) & 1u) && camPk[c] > best) { best = camPk[c]; bc = c; }
      used |= 1u << bc;
      ch[k] = (int)(~(unsigned)(best & 0xffffffffull));
    }
  }
  __syncthreads();

  const int c0 = ch[0], c1 = ch[1], c2 = ch[2];
  for (int i = tid; i < C2; i += 256) {
    int ix = is_[i];
    if (ix == c0 || ix == c1 || ix == c2) vs[i] = NEG_BIG;
  }
  __syncthreads();

  const float M = fdec(maxKey[b]);

  // sims rank -> winners gather
  {
    float v0 = (tid < C2) ? vs[tid] : NEG_BIG;
    int   i0 = (tid < C2) ? is_[tid] : 0x7fffffff;
    float v1 = (tid + 256 < C2) ? vs[tid + 256] : NEG_BIG;
    int   i1 = (tid + 256 < C2) ? is_[tid + 256] : 0x7fffffff;
    int r0 = 0, r1 = 0;
    const float4* v4 = (const float4*)vs;
    const int4*   q4 = (const int4*)is_;
    for (int m4 = 0; m4 < (C2p >> 2); ++m4) {
      float4 vm = v4[m4]; int4 im = q4[m4];
      r0 += (vm.x > v0) || (vm.x == v0 && im.x < i0);
      r0 += (vm.y > v0) || (vm.y == v0 && im.y < i0);
      r0 += (vm.z > v0) || (vm.z == v0 && im.z < i0);
      r0 += (vm.w > v0) || (vm.w == v0 && im.w < i0);
      r1 += (vm.x > v1) || (vm.x == v1 && im.x < i1);
      r1 += (vm.y > v1) || (vm.y == v1 && im.y < i1);
      r1 += (vm.z > v1) || (vm.z == v1 && im.z < i1);
      r1 += (vm.w > v1) || (vm.w == v1 && im.w < i1);
    }
    if (tid < C2 && v0 > -1.0e38f && r0 < 50) {
      int t = atomicAdd(&scnt, 1);
      if (t < 50) sbuf[t] = Srow[i0];
    }
    if (tid + 256 < C2 && v1 > -1.0e38f && r1 < 50) {
      int t = atomicAdd(&scnt, 1);
      if (t < 50) sbuf[t] = Srow[i1];
    }
    if (tid < 3) sbuf[50 + tid] = Srow[ch[tid]];
  }

  // cross rank -> exp-sum
  float myexp = 0.f, pl = 0.f;
  {
    float v0 = (tid < C) ? vb[tid] : NEG_BIG;
    int   i0 = (tid < C) ? ib[tid] : 0x7fffffff;
    float v1 = (tid + 256 < C) ? vb[tid + 256] : NEG_BIG;
    int   i1 = (tid + 256 < C) ? ib[tid + 256] : 0x7fffffff;
    int r0 = 0, r1 = 0;
    const float4* v4 = (const float4*)vb;
    const int4*   q4 = (const int4*)ib;
    for (int m4 = 0; m4 < (Cp >> 2); ++m4) {
      float4 vm = v4[m4]; int4 im = q4[m4];
      r0 += (vm.x > v0) || (vm.x == v0 && im.x < i0);
      r0 += (vm.y > v0) || (vm.y == v0 && im.y < i0);
      r0 += (vm.z > v0) || (vm.z == v0 && im.z < i0);
      r0 += (vm.w > v0) || (vm.w == v0 && im.w < i0);
      r1 += (vm.x > v1) || (vm.x == v1 && im.x < i1);
      r1 += (vm.y > v1) || (vm.y == v1 && im.y < i1);
      r1 += (vm.z > v1) || (vm.z == v1 && im.z < i1);
      r1 += (vm.w > v1) || (vm.w == v1 && im.w < i1);
    }
    if (tid < C && r0 < 50) myexp += expf((v0 - M) * INVT);
    if (tid + 256 < C && r1 < 50) myexp += expf((v1 - M) * INVT);
    if (tid < 8) {
      float pv = Srow[posBase + tid];
      myexp += expf((pv - M) * INVT);
      pl = (pv - M) * INVT;
    }
  }
  float stot = blockSum4(myexp, tid, red4);
  float plin = blockSum4(pl, tid, red4);
  if (tid == 0) {
    float lse = logf(stot);
    crossArr[b] = -(plin - 8.f * lse) * 0.125f;
  }

  if (tid < 64) {
    float v = (tid < 53) ? sbuf[tid] : NEG_BIG;
    float mm = v;
#pragma unroll
    for (int off = 1; off < 64; off <<= 1) mm = fmaxf(mm, __shfl_xor(mm, off));
    float e = (tid < 53) ? expf((v - mm) * INVT) : 0.f;
    float ss = e;
#pragma unroll
    for (int off = 1; off < 64; off <<= 1) ss += __shfl_xor(ss, off);
    float lse = logf(ss);
    float c = (tid >= 50 && tid < 53) ? ((v - mm) * INVT - lse) : 0.f;
#pragma unroll
    for (int off = 1; off < 64; off <<= 1) c += __shfl_xor(c, off);
    if (tid == 0) onlArr[b] = -c * (1.0f / 3.0f);
  }
}

// ---------------- kernel 3: per-camera means -> scalar ----------------
__global__ void finalize(const int* __restrict__ cams,
                         const float* __restrict__ ia,
                         const float* __restrict__ ca,
                         const float* __restrict__ oa,
                         float* __restrict__ out) {
  if (blockIdx.x == 0 && threadIdx.x == 0) {
    float s[8] = {}; float n[8] = {};
    for (int b = 0; b < B_SZ; ++b) {
      int c = cams[b];
      s[c] += ia[b] + ca[b] + oa[b];
      n[c] += 1.f;
    }
    float tot = 0.f;
    for (int c = 0; c < 8; ++c)
      if (n[c] > 0.f) tot += s[c] / n[c];
    out[0] = tot;
  }
}

extern "C" void kernel_launch(void* const* d_in, const int* in_sizes, int n_in,
                              void* d_out, int out_size, void* d_ws, size_t ws_size,
                              hipStream_t stream) {
  const float* features = (const float*)d_in[0];
  const int*   targets  = (const int*)d_in[1];
  const int*   cams     = (const int*)d_in[2];
  const float* mem      = (const float*)d_in[4];
  const int*   all_prx  = (const int*)d_in[6];

  float* ws = (float*)d_ws;
  float* A2  = ws;                               // 512*256 (interleaved rows)
  float* OUT = ws + 512 * D_DIM;                 // 512*32768 (rows 2b / 2b+1)
  char*  tail = (char*)(OUT + (size_t)512 * P_CNT);

  int*      prxArr = (int*)tail;                tail += B_SZ * 4;
  char* zbase = tail;
  unsigned* maxKey = (unsigned*)tail;           tail += B_SZ * 4;
  float*    intraS = (float*)tail;              tail += B_SZ * 4;
  int* cxSeg = (int*)tail;                      tail += B_SZ * NSEG * 4;
  int* smSeg = (int*)tail;                      tail += B_SZ * NSEG * 4;
  size_t zbytes = (size_t)(tail - zbase);
  float* intraArr = (float*)tail;               tail += B_SZ * 4;
  float* crossArr = (float*)tail;               tail += B_SZ * 4;
  float* onlArr   = (float*)tail;               tail += B_SZ * 4;
  float* cxVal = (float*)tail;                  tail += (size_t)B_SZ * CAPT * 4;
  int*   cxIdx = (int*)tail;                    tail += (size_t)B_SZ * CAPT * 4;
  float* smVal = (float*)tail;                  tail += (size_t)B_SZ * CAPT * 4;
  int*   smIdx = (int*)tail;                    tail += (size_t)B_SZ * CAPT * 4;

  hipMemsetAsync(zbase, 0, zbytes, stream);
  prep_kernel<<<B_SZ, D_DIM, 0, stream>>>(features, targets, all_prx, mem, A2, prxArr);
  gemm_fused<<<1024, 256, 0, stream>>>(A2, mem, OUT, prxArr, cams,
      maxKey, intraS, cxSeg, cxVal, cxIdx, smSeg, smVal, smIdx);
  fixup<<<B_SZ, 256, 0, stream>>>(OUT, prxArr, maxKey,
      cxSeg, cxVal, cxIdx, smSeg, smVal, smIdx);
  merge<<<B_SZ, 256, 0, stream>>>(OUT, prxArr, maxKey, intraS,
      cxSeg, cxVal, cxIdx, smSeg, smVal, smIdx, intraArr, crossArr, onlArr);
  finalize<<<1, 64, 0, stream>>>(cams, intraArr, crossArr, onlArr, (float*)d_out);
}